// Round 14
// baseline (83.128 us; speedup 1.0000x reference)
//
#include <hip/hip_runtime.h>

typedef __attribute__((ext_vector_type(8))) short bf16x8;
typedef __attribute__((ext_vector_type(4))) float f32x4;

#define MFMA16(A, B, C) __builtin_amdgcn_mfma_f32_16x16x32_bf16(A, B, C, 0, 0, 0)

__device__ __forceinline__ unsigned short f2bf(float f) {
  union { float f; unsigned int u; } v; v.f = f;
  return (unsigned short)((v.u + 0x7fffu + ((v.u >> 16) & 1u)) >> 16);
}
#define PK(LO, HI) (((unsigned int)f2bf(LO)) | ((unsigned int)f2bf(HI) << 16))

// raw barrier: fence LDS for cross-wave visibility, leave global loads in flight
#define BAR() do {                                              \
    asm volatile("s_waitcnt lgkmcnt(0)" ::: "memory");          \
    __builtin_amdgcn_s_barrier();                               \
    asm volatile("" ::: "memory");                              \
  } while (0)

// prep: f32 weights -> bf16 per-K-step images (+cu_comp fused), XOR swizzle baked.
// img[s][o*64+c] = bf16( w[o][ (s&1)*64 + (c ^ ((o&7)<<3)) ][ s>>1 ] ), s=2t+hf
__global__ __launch_bounds__(256) void prep_kernel(
    const float* __restrict__ kw, const float* __restrict__ vw,
    unsigned short* __restrict__ imgK, unsigned short* __restrict__ imgV,
    int KSd,
    const int* __restrict__ cuin, float* __restrict__ outf,
    int cubase, int nb, int strideh) {
  __shared__ float wlds[128 * 33];
  int tid = threadIdx.x, bid = blockIdx.x;
  int sel = bid >> 7, o = bid & 127;
  int nel = 128 * KSd;
  int ksh = (KSd == 32) ? 5 : ((KSd == 16) ? 4 : 31 - __clz(KSd));
  int pad = KSd + 1;
  const float* wo = (sel ? vw : kw) + (size_t)o * nel;
  unsigned short* dst = sel ? imgV : imgK;
  for (int idx = tid; idx < nel; idx += 256) {
    int i = idx >> ksh, t = idx & (KSd - 1);
    wlds[i * pad + t] = wo[idx];
  }
  __syncthreads();
  int swE = (o & 7) << 3;
  for (int idx = tid; idx < nel; idx += 256) {
    int s = idx >> 6, c = idx & 63;
    int i = ((s & 1) << 6) + (c ^ swE);
    dst[((size_t)s << 13) + (o << 6) + c] = f2bf(wlds[i * pad + (s >> 1)]);
  }
  if (bid == 0 && tid <= nb) outf[cubase + tid] = (float)(cuin[tid] / strideh);
}

// ===== fast path: BM=128 tap-pair, K-SPLIT waves, B direct-to-register =====
// 256 blocks (sel,h,128-row M-tile); 512 thr = 8 waves = 2M x 2N x 2Ksplit.
// Wave owns 64 rows x 64 cols x half-K: per substep 4 ds_read_b128 -> 16 MFMA
// (0.25 reads/MFMA). A staged once per tap-pair (130 slices, kv read ONCE);
// B frags double-buffered in regs from L2-resident swizzled img. One lgkm-only
// barrier per pair + one before the epilogue LDS reuse (round-13 NaN fix).
__global__ __launch_bounds__(512) void gemm_ksplit_kernel(
    const float* __restrict__ kv,
    const float* __restrict__ biasK, const float* __restrict__ biasV,
    const unsigned short* __restrict__ imgK, const unsigned short* __restrict__ imgV,
    float* __restrict__ out,
    int vbase, int nc, int ltot, int tokmax, int seqb, int mtiles) {
  __shared__ __align__(16) unsigned short T[2][16640];   // 130 slices x 256B, x2
  int tid = threadIdx.x, bid = blockIdx.x;
  int per_sel = 8 * mtiles;
  int sel = (bid >= per_sel) ? 1 : 0;
  int rem = bid - sel * per_sel;
  int h = rem / mtiles, mtile = rem - h * mtiles;
  int m0 = mtile * 128;
  const unsigned short* img = sel ? imgV : imgK;
  const float* bias = sel ? biasV : biasK;
  int outbase = sel ? vbase : 0;
  int lane = tid & 63, wid = tid >> 6;
  int kw = wid >> 2;                    // K-half 0/1
  int wm = (wid >> 1) & 1, wn = wid & 1;// 2M x 2N
  int l15 = lane & 15, l4 = lane >> 4;

  // ---- batch geometry: row r token = btok0 + J(r)*16 + tap, J(r)=r+(r>=rb) ----
  int b0 = m0 / nc, c0 = m0 - b0 * nc;
  int btok0 = b0 * seqb + c0 * 16;
  int rb = nc - c0;                     // single boundary (nc>=128 guard)

  // ---- A staging: 130 slices, 16 threads x 32B each, 4 passes + tail ----
  int sjl = tid >> 4, sje = tid & 15;
  int soff = sel * 1024 + h * 128 + sje * 8;

  // ---- A fragment constants: 4 mi frags cover the wave's 64 rows ----
  int kb0 = kw * 64 + l4 * 16;          // K-half baked into byte offset
  int jbL[4], jswL[4], jbH[4], jswH[4];
#pragma unroll
  for (int mi = 0; mi < 4; ++mi) {
    int r = wm * 64 + mi * 16 + l15;
    int j = r + (r >= rb ? 1 : 0);
    jbL[mi] = j * 256;       jswL[mi] = (j & 7) << 4;
    jbH[mi] = (j + 1) * 256; jswH[mi] = ((j + 1) & 7) << 4;
  }

  // ---- B fragment elem offsets (swizzle-baked, K-half baked) ----
  int bo[4];
#pragma unroll
  for (int ni = 0; ni < 4; ++ni) {
    int o_ = wn * 64 + ni * 16 + l15;
    bo[ni] = o_ * 64 + ((kw * 32 + l4 * 8) ^ ((o_ & 7) << 3));
  }

  f32x4 zz = {0.f, 0.f, 0.f, 0.f};
  f32x4 acc[4][4];
#pragma unroll
  for (int mi = 0; mi < 4; ++mi)
#pragma unroll
    for (int ni = 0; ni < 4; ++ni) acc[mi][ni] = zz;

  float4 ta[5], tb[5];
  bf16x8 Bc[4], Bn[4];

#define STAGE_LOAD(P) do {                                                       \
    _Pragma("unroll")                                                            \
    for (int q_ = 0; q_ < 4; ++q_) {                                             \
      int t_ = btok0 + (q_ * 32 + sjl) * 16 + (P); if (t_ > tokmax) t_ = tokmax; \
      const float* a_ = kv + ((size_t)t_ << 11) + soff;                          \
      ta[q_] = *(const float4*)a_; tb[q_] = *(const float4*)(a_ + 4);            \
    }                                                                            \
    if (sjl < 2) {                                                               \
      int t_ = btok0 + (128 + sjl) * 16 + (P); if (t_ > tokmax) t_ = tokmax;     \
      const float* a_ = kv + ((size_t)t_ << 11) + soff;                          \
      ta[4] = *(const float4*)a_; tb[4] = *(const float4*)(a_ + 4);              \
    }                                                                            \
  } while (0)

#define T_WRITE(TB) do {                                                         \
    char* tp_ = (char*)(TB);                                                     \
    _Pragma("unroll")                                                            \
    for (int q_ = 0; q_ < 4; ++q_) {                                             \
      int js_ = q_ * 32 + sjl;                                                   \
      *(uint4*)(tp_ + js_ * 256 + ((sje * 16) ^ ((js_ & 7) << 4))) =             \
        make_uint4(PK(ta[q_].x, ta[q_].y), PK(ta[q_].z, ta[q_].w),               \
                   PK(tb[q_].x, tb[q_].y), PK(tb[q_].z, tb[q_].w));              \
    }                                                                            \
    if (sjl < 2) {                                                               \
      int js_ = 128 + sjl;                                                       \
      *(uint4*)(tp_ + js_ * 256 + ((sje * 16) ^ ((js_ & 7) << 4))) =             \
        make_uint4(PK(ta[4].x, ta[4].y), PK(ta[4].z, ta[4].w),                   \
                   PK(tb[4].x, tb[4].y), PK(tb[4].z, tb[4].w));                  \
    }                                                                            \
  } while (0)

#define B_LOADR(DST, S) do {                                                     \
    const unsigned short* bp_ = img + ((size_t)(S) << 13);                       \
    _Pragma("unroll")                                                            \
    for (int ni = 0; ni < 4; ++ni) DST[ni] = *(const bf16x8*)(bp_ + bo[ni]);     \
  } while (0)

  // substep: tap-half HF, A-frag set JB/JSW, B-frag set BSET (this wave's kk)
#define SUBSTEP(HF, JB, JSW, BSET) do {                                          \
    const char* tc_ = (const char*)T[tcur];                                      \
    __builtin_amdgcn_s_setprio(1);                                               \
    int kcA_ = (HF) * 128 + kb0;                                                 \
    bf16x8 a_[4];                                                                \
    _Pragma("unroll")                                                            \
    for (int mi = 0; mi < 4; ++mi)                                               \
      a_[mi] = *(const bf16x8*)(tc_ + JB[mi] + (kcA_ ^ JSW[mi]));                \
    _Pragma("unroll")                                                            \
    for (int mi = 0; mi < 4; ++mi)                                               \
    _Pragma("unroll")                                                            \
      for (int ni = 0; ni < 4; ++ni)                                             \
        acc[mi][ni] = MFMA16(a_[mi], BSET[ni], acc[mi][ni]);                     \
    __builtin_amdgcn_s_setprio(0);                                               \
  } while (0)

  // ---- prologue: T[0] = pair-0 A; Bc = B(0); Bn = B(1) ----
  int tcur = 0;
  STAGE_LOAD(0);
  T_WRITE(T[0]);
  B_LOADR(Bc, 0);
  B_LOADR(Bn, 1);
  BAR();

  // steps per pair p: 2p, 2p+1, 2p+32, 2p+33 (taps p / p+16, halves 0/1)
  for (int p = 0; p < 16; ++p) {
    if (p < 15) STAGE_LOAD(p + 1);               // HBM issue-early (written at q3)
    SUBSTEP(0, jbL, jswL, Bc);                   // q0 uses B(2p)
    B_LOADR(Bc, 2 * p + 32);
    SUBSTEP(1, jbL, jswL, Bn);                   // q1 uses B(2p+1)
    B_LOADR(Bn, 2 * p + 33);
    SUBSTEP(0, jbH, jswH, Bc);                   // q2 uses B(2p+32)
    if (p < 15) B_LOADR(Bc, 2 * p + 2);
    SUBSTEP(1, jbH, jswH, Bn);                   // q3 uses B(2p+33)
    if (p < 15) {
      B_LOADR(Bn, 2 * p + 3);
      T_WRITE(T[tcur ^ 1]);                      // next pair's A (issued at q0)
      BAR();
    }
    tcur ^= 1;
  }

  // ---- epilogue: cross-K-half reduce via LDS (T reused), bias, f32 store ----
  BAR();   // round-13 NaN fix: all waves' final ds_reads from T must complete
           // before kw==1 waves overwrite T with f32 accumulators.
  float* red = (float*)T;                        // 64 KB of the 66.5 KB
  int widx = wm * 2 + wn;
  if (kw == 1) {
#pragma unroll
    for (int mi = 0; mi < 4; ++mi)
#pragma unroll
      for (int ni = 0; ni < 4; ++ni)
        *(f32x4*)(red + (size_t)(((widx * 16 + mi * 4 + ni) * 64 + lane)) * 4) = acc[mi][ni];
  }
  BAR();
  if (kw == 0) {
#pragma unroll
    for (int ni = 0; ni < 4; ++ni) {
      int o_ = wn * 64 + ni * 16 + l15;
      float bv_ = bias[o_];
#pragma unroll
      for (int mi = 0; mi < 4; ++mi) {
        f32x4 other = *(const f32x4*)(red + (size_t)(((widx * 16 + mi * 4 + ni) * 64 + lane)) * 4);
        f32x4 v_ = acc[mi][ni];
        int lb_ = m0 + wm * 64 + mi * 16 + l4 * 4;
#pragma unroll
        for (int jj = 0; jj < 4; ++jj) {
          int ll_ = lb_ + jj;
          if (ll_ < ltot)
            out[(size_t)outbase + (size_t)ll_ * 1024 + h * 128 + o_] =
                v_[jj] + other[jj] + bv_;
        }
      }
    }
  }
}

// ===== fallback: round-6-proven generic kernel (swizzled img or gather) =====
__global__ __launch_bounds__(512) void gemm_kernel(
    const float* __restrict__ kv,
    const float* __restrict__ biasK, const float* __restrict__ biasV,
    const unsigned short* __restrict__ imgK, const unsigned short* __restrict__ imgV,
    const float* __restrict__ kw, const float* __restrict__ vw,
    float* __restrict__ out,
    int selbase, int vbase, int nc, int ltot, int nsteps,
    int tokmax, int seqb, int strideh, int KSd, int mtiles) {
  __shared__ __align__(16) unsigned short As[2][4096];
  __shared__ __align__(16) unsigned short Bsf[2][8192];
  int tid = threadIdx.x, bid = blockIdx.x;
  int per_sel = 8 * mtiles;
  int sel = selbase + (bid >= per_sel);
  int rem = (bid >= per_sel) ? bid - per_sel : bid;
  int h = rem / mtiles, mtile = rem - h * mtiles;
  int m0 = mtile * 64;
  const unsigned short* img = sel ? imgV : imgK;
  const float* bias = sel ? biasV : biasK;
  const float* wsel = sel ? vw : kw;
  int outbase = sel ? vbase : 0;
  int lane = tid & 63, wid = tid >> 6;
  int warpM = wid >> 2, warpN = wid & 3;

  int aj = tid & 7, r = tid >> 3;
  int l = m0 + r; if (l > ltot - 1) l = ltot - 1;
  int b = l / nc, c = l - b * nc;
  int btok = b * seqb + c * strideh;
  const float* abase = kv + sel * 1024 + h * 128 + aj * 4;
  int swr = (r & 7) << 3;
  int awb0 = r * 128 + 2 * ((aj * 4) ^ swr);
  int awb1 = r * 128 + 2 * ((aj * 4 + 32) ^ swr);

  int o_g = tid >> 3, cb_g = (tid & 7) << 3;
  int ib_g = cb_g ^ ((o_g & 7) << 3);
  const float* g0 = wsel + (size_t)o_g * (KSd << 7);
  const float* g1 = g0 + ((size_t)64 * (KSd << 7));

  int kb0 = (lane >> 4) * 16;
  int arb[2], asw[2], brb[2], bsw[2];
#pragma unroll
  for (int mi = 0; mi < 2; ++mi) {
    int rr = warpM * 32 + mi * 16 + (lane & 15);
    arb[mi] = rr * 128; asw[mi] = (rr & 7) << 4;
  }
#pragma unroll
  for (int ni = 0; ni < 2; ++ni) {
    int oo = warpN * 32 + ni * 16 + (lane & 15);
    brb[ni] = oo * 128; bsw[ni] = (oo & 7) << 4;
  }

  f32x4 acc[2][2];
  f32x4 zz = {0.f, 0.f, 0.f, 0.f};
#pragma unroll
  for (int a = 0; a < 2; ++a)
#pragma unroll
    for (int b2 = 0; b2 < 2; ++b2) acc[a][b2] = zz;

  float4 Af0, Af1;
  uint4 Brr[2];

#define LOAD_STEP(S) do {                                                        \
    int tok_ = btok + ((S) >> 1); if (tok_ > tokmax) tok_ = tokmax;              \
    const float* ap_ = abase + ((size_t)tok_ << 11) + (((S) & 1) << 6);          \
    Af0 = *(const float4*)ap_;                                                   \
    Af1 = *(const float4*)(ap_ + 32);                                            \
    if (img) {                                                                   \
      const uint4* bsrc_ = (const uint4*)(img + ((size_t)(S) << 13));            \
      Brr[0] = bsrc_[tid];                                                       \
      Brr[1] = bsrc_[512 + tid];                                                 \
    } else {                                                                     \
      int t_ = (S) >> 1, i0_ = (((S) & 1) << 6) + ib_g;                          \
      unsigned int p0_[4], p1_[4];                                               \
      _Pragma("unroll")                                                          \
      for (int m = 0; m < 4; ++m) {                                              \
        p0_[m] = (unsigned int)f2bf(g0[(i0_ + 2*m) * KSd + t_])                  \
               | ((unsigned int)f2bf(g0[(i0_ + 2*m + 1) * KSd + t_]) << 16);     \
        p1_[m] = (unsigned int)f2bf(g1[(i0_ + 2*m) * KSd + t_])                  \
               | ((unsigned int)f2bf(g1[(i0_ + 2*m + 1) * KSd + t_]) << 16);     \
      }                                                                          \
      Brr[0] = make_uint4(p0_[0], p0_[1], p0_[2], p0_[3]);                       \
      Brr[1] = make_uint4(p1_[0], p1_[1], p1_[2], p1_[3]);                       \
    }                                                                            \
  } while (0)

#define WRITE_STEP(DB) do {                                                      \
    *(uint2*)((char*)As[DB] + awb0) = make_uint2(PK(Af0.x, Af0.y), PK(Af0.z, Af0.w)); \
    *(uint2*)((char*)As[DB] + awb1) = make_uint2(PK(Af1.x, Af1.y), PK(Af1.z, Af1.w)); \
    uint4* bdst_ = (uint4*)Bsf[DB];                                              \
    bdst_[tid] = Brr[0];                                                         \
    bdst_[512 + tid] = Brr[1];                                                   \
  } while (0)

#define COMPUTE_STEP(CB) do {                                                    \
    _Pragma("unroll")                                                            \
    for (int kk = 0; kk < 2; ++kk) {                                             \
      bf16x8 af_[2], bg_[2];                                                     \
      int kc_ = kk * 64 + kb0;                                                   \
      _Pragma("unroll")                                                          \
      for (int mi = 0; mi < 2; ++mi)                                             \
        af_[mi] = *(const bf16x8*)((const char*)As[CB] + arb[mi] + (kc_ ^ asw[mi])); \
      _Pragma("unroll")                                                          \
      for (int ni = 0; ni < 2; ++ni)                                             \
        bg_[ni] = *(const bf16x8*)((const char*)Bsf[CB] + brb[ni] + (kc_ ^ bsw[ni])); \
      _Pragma("unroll")                                                          \
      for (int mi = 0; mi < 2; ++mi)                                             \
      _Pragma("unroll")                                                          \
        for (int ni = 0; ni < 2; ++ni)                                           \
          acc[mi][ni] = MFMA16(af_[mi], bg_[ni], acc[mi][ni]);                   \
    }                                                                            \
  } while (0)

  LOAD_STEP(0);
  WRITE_STEP(0);
  __syncthreads();
  int cur = 0;
  for (int s = 0; s < nsteps; ++s) {
    if (s + 1 < nsteps) LOAD_STEP(s + 1);
    COMPUTE_STEP(cur);
    if (s + 1 < nsteps) WRITE_STEP(cur ^ 1);
    __syncthreads();
    cur ^= 1;
  }

  int l15 = lane & 15, l4 = lane >> 4;
#pragma unroll
  for (int ni = 0; ni < 2; ++ni) {
    int o = warpN * 32 + ni * 16 + l15;
    float bv = bias[o];
#pragma unroll
    for (int mi = 0; mi < 2; ++mi) {
      int lb = m0 + warpM * 32 + mi * 16 + l4 * 4;
      f32x4 v = acc[mi][ni];
#pragma unroll
      for (int jj = 0; jj < 4; ++jj) {
        int ll = lb + jj;
        if (ll < ltot)
          out[(size_t)outbase + (size_t)ll * 1024 + h * 128 + o] = v[jj] + bv;
      }
    }
  }
}

extern "C" void kernel_launch(void* const* d_in, const int* in_sizes, int n_in,
                              void* d_out, int out_size, void* d_ws, size_t ws_size,
                              hipStream_t stream) {
  // ---- identify inputs by element count (robust to order) ----
  long kvN = 0; int kvi = 0;
  for (int i = 0; i < n_in; ++i)
    if ((long)in_sizes[i] > kvN) { kvN = in_sizes[i]; kvi = i; }
  const float* kv = (const float*)d_in[kvi];
  const float *w0 = nullptr, *w1 = nullptr, *b0 = nullptr, *b1 = nullptr;
  const int* cuin = nullptr;
  int KSd = 32, nb = 4;
  for (int i = 0; i < n_in; ++i) {
    if (i == kvi) continue;
    int sz = in_sizes[i];
    if (sz == 128) { if (!b0) b0 = (const float*)d_in[i]; else if (!b1) b1 = (const float*)d_in[i]; }
    else if (sz <= 32) { nb = sz - 1; cuin = (const int*)d_in[i]; }
    else if (sz >= 4096) {
      if (!w0) { w0 = (const float*)d_in[i]; KSd = sz / 16384; }
      else if (!w1) w1 = (const float*)d_in[i];
    }
  }
  if (!w0) w0 = (const float*)d_in[2];
  if (!b0) b0 = (const float*)d_in[3];
  if (!w1) w1 = (const float*)d_in[4];
  if (!b1) b1 = (const float*)d_in[5];
  if (!cuin) cuin = (const int*)d_in[1];
  if (nb < 1) nb = 4;

  float* out = (float*)d_out;

  // ---- geometry derived from reported sizes ----
  int cubase  = out_size - (nb + 1);
  int vbase   = cubase >> 1;
  int ltot    = cubase >> 11;
  int nc      = ltot / nb;
  int nsteps  = 2 * KSd;
  long tokens = kvN >> 11;
  int seqb    = (int)(tokens / nb);
  int strideh = (nc > 1) ? (seqb - KSd) / (nc - 1) : KSd;
  int tokmax  = (int)tokens - 1;
  int mtiles  = (ltot + 63) >> 6;      // 64-row tiles (fallback)
  int mt128   = (ltot + 127) >> 7;     // 128-row tiles (fast path)
  int per_sel = 8 * mtiles;

  size_t imgel = (size_t)nsteps * 8192;
  size_t imgbytes = imgel * 2;
  bool fast = (KSd == 32) && (strideh == 16) && (nc >= 128) &&
              (ws_size >= 2 * imgbytes);
  if (fast) {
    unsigned short* imgK = (unsigned short*)d_ws;
    unsigned short* imgV = imgK + imgel;
    prep_kernel<<<256, 256, 0, stream>>>(w0, w1, imgK, imgV, KSd,
                                         cuin, out, cubase, nb, strideh);
    gemm_ksplit_kernel<<<2 * 8 * mt128, 512, 0, stream>>>(
        kv, b0, b1, imgK, imgV, out, vbase, nc, ltot, tokmax, seqb, mt128);
  } else if (ws_size >= 2 * imgbytes) {
    unsigned short* imgK = (unsigned short*)d_ws;
    unsigned short* imgV = imgK + imgel;
    prep_kernel<<<256, 256, 0, stream>>>(w0, w1, imgK, imgV, KSd,
                                         cuin, out, cubase, nb, strideh);
    gemm_kernel<<<2 * per_sel, 512, 0, stream>>>(kv, b0, b1, imgK, imgV, w0, w1, out,
        0, vbase, nc, ltot, nsteps, tokmax, seqb, strideh, KSd, mtiles);
  } else {
    prep_kernel<<<256, 256, 0, stream>>>(w0, w1, (unsigned short*)d_ws,
                                         (unsigned short*)d_ws, 0,
                                         cuin, out, cubase, nb, strideh);
    gemm_kernel<<<2 * per_sel, 512, 0, stream>>>(kv, b0, b1,
        (const unsigned short*)nullptr, (const unsigned short*)nullptr, w0, w1, out,
        0, vbase, nc, ltot, nsteps, tokmax, seqb, strideh, KSd, mtiles);
  }
}

// Round 15
// 76.432 us; speedup vs baseline: 1.0876x; 1.0876x over previous
//
#include <hip/hip_runtime.h>

typedef __attribute__((ext_vector_type(8))) short bf16x8;
typedef __attribute__((ext_vector_type(4))) float f32x4;

#define MFMA16(A, B, C) __builtin_amdgcn_mfma_f32_16x16x32_bf16(A, B, C, 0, 0, 0)

__device__ __forceinline__ unsigned short f2bf(float f) {
  union { float f; unsigned int u; } v; v.f = f;
  return (unsigned short)((v.u + 0x7fffu + ((v.u >> 16) & 1u)) >> 16);
}
#define PK(LO, HI) (((unsigned int)f2bf(LO)) | ((unsigned int)f2bf(HI) << 16))

// raw barrier: fence LDS for cross-wave visibility, leave global loads in flight
#define BAR() do {                                              \
    asm volatile("s_waitcnt lgkmcnt(0)" ::: "memory");          \
    __builtin_amdgcn_s_barrier();                               \
    asm volatile("" ::: "memory");                              \
  } while (0)

// prep: f32 weights -> bf16 per-K-step images (+cu_comp fused), XOR swizzle baked.
// img[s][o*64+c] = bf16( w[o][ (s&1)*64 + (c ^ ((o&7)<<3)) ][ s>>1 ] ), s=2t+hf
// wlds padded stride KSd+1 (transpose-read is a 32-way bank conflict unpadded).
__global__ __launch_bounds__(256) void prep_kernel(
    const float* __restrict__ kw, const float* __restrict__ vw,
    unsigned short* __restrict__ imgK, unsigned short* __restrict__ imgV,
    int KSd,
    const int* __restrict__ cuin, float* __restrict__ outf,
    int cubase, int nb, int strideh) {
  __shared__ float wlds[128 * 33];
  int tid = threadIdx.x, bid = blockIdx.x;
  int sel = bid >> 7, o = bid & 127;
  int nel = 128 * KSd;
  int ksh = (KSd == 32) ? 5 : ((KSd == 16) ? 4 : 31 - __clz(KSd));
  int pad = KSd + 1;
  const float* wo = (sel ? vw : kw) + (size_t)o * nel;
  unsigned short* dst = sel ? imgV : imgK;
  for (int idx = tid; idx < nel; idx += 256) {
    int i = idx >> ksh, t = idx & (KSd - 1);
    wlds[i * pad + t] = wo[idx];
  }
  __syncthreads();
  int swE = (o & 7) << 3;
  for (int idx = tid; idx < nel; idx += 256) {
    int s = idx >> 6, c = idx & 63;
    int i = ((s & 1) << 6) + (c ^ swE);
    dst[((size_t)s << 13) + (o << 6) + c] = f2bf(wlds[i * pad + (s >> 1)]);
  }
  if (bid == 0 && tid <= nb) outf[cubase + tid] = (float)(cuin[tid] / strideh);
}

// ===== fast path (round-11 proven, 77.4 us): BM=128 tap-pair, LDS-B =====
// One (sel,h,128-row M-tile) per block; 512 thr = 8 waves (2M x 4N), wave tile
// 64x32 (4mi x 2ni). A staged once per tap-pair (130 token slices serve taps
// p and p+16); B staged per step in LDS, register-prefetched 2 substeps ahead.
// Raw lgkm-only barriers; 1 barrier per substep.
__global__ __launch_bounds__(512) void gemm_big_kernel(
    const float* __restrict__ kv,
    const float* __restrict__ biasK, const float* __restrict__ biasV,
    const unsigned short* __restrict__ imgK, const unsigned short* __restrict__ imgV,
    float* __restrict__ out,
    int vbase, int nc, int ltot, int tokmax, int seqb, int mtiles) {
  __shared__ __align__(16) unsigned short T[2][16640];   // 130 slices x 256B, x2
  __shared__ __align__(16) unsigned short Bs[2][8192];   // B step buffers (2x16KB)
  int tid = threadIdx.x, bid = blockIdx.x;
  int per_sel = 8 * mtiles;
  int sel = (bid >= per_sel) ? 1 : 0;
  int rem = bid - sel * per_sel;
  int h = rem / mtiles, mtile = rem - h * mtiles;
  int m0 = mtile * 128;
  const unsigned short* img = sel ? imgV : imgK;
  const float* bias = sel ? biasV : biasK;
  int outbase = sel ? vbase : 0;
  int lane = tid & 63, wid = tid >> 6;
  int wm = wid >> 2, wn = wid & 3;            // 2M x 4N wave grid
  int l15 = lane & 15, l4 = lane >> 4;

  // ---- batch geometry: row r token = btok0 + J(r)*16 + tap, J(r)=r+(r>=rb) ----
  int b0 = m0 / nc, c0 = m0 - b0 * nc;
  int btok0 = b0 * seqb + c0 * 16;
  int rb = nc - c0;                            // single boundary (nc>=128 guard)

  // ---- A staging: 130 slices, 16 threads x 32B each, 4 full passes + tail ----
  int sjl = tid >> 4, sje = tid & 15;
  int soff = sel * 1024 + h * 128 + sje * 8;

  // ---- A fragment constants: 4 mi frags cover the wave's 64 rows ----
  int kb0 = l4 * 16;
  int jbL[4], jswL[4], jbH[4], jswH[4];
#pragma unroll
  for (int mi = 0; mi < 4; ++mi) {
    int r = wm * 64 + mi * 16 + l15;
    int j = r + (r >= rb ? 1 : 0);
    jbL[mi] = j * 256;       jswL[mi] = (j & 7) << 4;
    jbH[mi] = (j + 1) * 256; jswH[mi] = ((j + 1) & 7) << 4;
  }

  // ---- B fragment constants (swizzled Bs layout, proven) ----
  int o0 = wn * 32 + l15, o1 = o0 + 16;
  int brb0 = o0 * 128, bsw0 = (o0 & 7) << 4;
  int brb1 = o1 * 128, bsw1 = (o1 & 7) << 4;

  f32x4 zz = {0.f, 0.f, 0.f, 0.f};
  f32x4 acc[4][2];
#pragma unroll
  for (int mi = 0; mi < 4; ++mi) { acc[mi][0] = zz; acc[mi][1] = zz; }

  float4 ta[5], tb[5];
  uint4 BrA0, BrA1, BrB0, BrB1;

#define STAGE_LOAD(P) do {                                                       \
    _Pragma("unroll")                                                            \
    for (int q_ = 0; q_ < 4; ++q_) {                                             \
      int t_ = btok0 + (q_ * 32 + sjl) * 16 + (P); if (t_ > tokmax) t_ = tokmax; \
      const float* a_ = kv + ((size_t)t_ << 11) + soff;                          \
      ta[q_] = *(const float4*)a_; tb[q_] = *(const float4*)(a_ + 4);            \
    }                                                                            \
    if (sjl < 2) {                                                               \
      int t_ = btok0 + (128 + sjl) * 16 + (P); if (t_ > tokmax) t_ = tokmax;     \
      const float* a_ = kv + ((size_t)t_ << 11) + soff;                          \
      ta[4] = *(const float4*)a_; tb[4] = *(const float4*)(a_ + 4);              \
    }                                                                            \
  } while (0)

#define T_WRITE(TB) do {                                                         \
    char* tp_ = (char*)(TB);                                                     \
    _Pragma("unroll")                                                            \
    for (int q_ = 0; q_ < 4; ++q_) {                                             \
      int js_ = q_ * 32 + sjl;                                                   \
      *(uint4*)(tp_ + js_ * 256 + ((sje * 16) ^ ((js_ & 7) << 4))) =             \
        make_uint4(PK(ta[q_].x, ta[q_].y), PK(ta[q_].z, ta[q_].w),               \
                   PK(tb[q_].x, tb[q_].y), PK(tb[q_].z, tb[q_].w));              \
    }                                                                            \
    if (sjl < 2) {                                                               \
      int js_ = 128 + sjl;                                                       \
      *(uint4*)(tp_ + js_ * 256 + ((sje * 16) ^ ((js_ & 7) << 4))) =             \
        make_uint4(PK(ta[4].x, ta[4].y), PK(ta[4].z, ta[4].w),                   \
                   PK(tb[4].x, tb[4].y), PK(tb[4].z, tb[4].w));                  \
    }                                                                            \
  } while (0)

#define B_LOAD(R0, R1, S) do {                                                   \
    const uint4* bsrc_ = (const uint4*)(img + ((size_t)(S) << 13));              \
    R0 = bsrc_[tid];                                                             \
    R1 = bsrc_[512 + tid];                                                       \
  } while (0)

#define B_WRITE(DB, R0, R1) do {                                                 \
    uint4* bdst_ = (uint4*)Bs[DB];                                               \
    bdst_[tid] = R0;                                                             \
    bdst_[512 + tid] = R1;                                                       \
  } while (0)

#define SUBSTEP(HF, JB, JSW, BB) do {                                            \
    const char* tc_ = (const char*)T[tcur];                                      \
    const char* bc_ = (const char*)Bs[BB];                                       \
    __builtin_amdgcn_s_setprio(1);                                               \
    _Pragma("unroll")                                                            \
    for (int kk = 0; kk < 2; ++kk) {                                             \
      int kcA_ = (HF) * 128 + kk * 64 + kb0;                                     \
      int kcB_ = kk * 64 + kb0;                                                  \
      bf16x8 b0_ = *(const bf16x8*)(bc_ + brb0 + (kcB_ ^ bsw0));                 \
      bf16x8 b1_ = *(const bf16x8*)(bc_ + brb1 + (kcB_ ^ bsw1));                 \
      _Pragma("unroll")                                                          \
      for (int mi = 0; mi < 4; ++mi) {                                           \
        bf16x8 a_ = *(const bf16x8*)(tc_ + JB[mi] + (kcA_ ^ JSW[mi]));           \
        acc[mi][0] = MFMA16(a_, b0_, acc[mi][0]);                                \
        acc[mi][1] = MFMA16(a_, b1_, acc[mi][1]);                                \
      }                                                                          \
    }                                                                            \
    __builtin_amdgcn_s_setprio(0);                                               \
  } while (0)

  // ---- prologue: Bs[0]=B(0); BrB=B(1); BrA=B(32); T[0]=pair-0 A ----
  int tcur = 0;
  STAGE_LOAD(0);
  T_WRITE(T[0]);
  B_LOAD(BrA0, BrA1, 0);
  B_WRITE(0, BrA0, BrA1);
  B_LOAD(BrB0, BrB1, 1);
  B_LOAD(BrA0, BrA1, 32);
  BAR();

  // steps consumed per pair p: 2p, 2p+1, 2p+32, 2p+33 (taps p / p+16, halves 0/1)
  for (int p = 0; p < 16; ++p) {
    // ---- q0: tap p half 0 (Bs[0]) ----
    if (p < 15) STAGE_LOAD(p + 1);               // HBM issue-early (drained at q3)
    SUBSTEP(0, jbL, jswL, 0);
    B_WRITE(1, BrB0, BrB1);                      // step 2p+1
    B_LOAD(BrB0, BrB1, 2 * p + 33);
    BAR();
    // ---- q1: tap p half 1 (Bs[1]) ----
    SUBSTEP(1, jbL, jswL, 1);
    B_WRITE(0, BrA0, BrA1);                      // step 2p+32
    if (p < 15) B_LOAD(BrA0, BrA1, 2 * p + 2);
    BAR();
    // ---- q2: tap p+16 half 0 (Bs[0]) ----
    SUBSTEP(0, jbH, jswH, 0);
    B_WRITE(1, BrB0, BrB1);                      // step 2p+33
    if (p < 15) B_LOAD(BrB0, BrB1, 2 * p + 3);
    BAR();
    // ---- q3: tap p+16 half 1 (Bs[1]) ----
    SUBSTEP(1, jbH, jswH, 1);
    if (p < 15) {
      B_WRITE(0, BrA0, BrA1);                    // step 2p+2
      B_LOAD(BrA0, BrA1, 2 * p + 34);
      T_WRITE(T[tcur ^ 1]);                      // next pair's A (issued at q0)
      BAR();
    }
    tcur ^= 1;
  }

  // ---- epilogue: bias + f32 store (guarded) ----
#pragma unroll
  for (int ni = 0; ni < 2; ++ni) {
    int o_ = wn * 32 + ni * 16 + l15;
    float bv_ = bias[o_];
#pragma unroll
    for (int mi = 0; mi < 4; ++mi) {
      int lb_ = m0 + wm * 64 + mi * 16 + l4 * 4;
      f32x4 v_ = acc[mi][ni];
#pragma unroll
      for (int jj = 0; jj < 4; ++jj) {
        int ll_ = lb_ + jj;
        if (ll_ < ltot)
          out[(size_t)outbase + (size_t)ll_ * 1024 + h * 128 + o_] = v_[jj] + bv_;
      }
    }
  }
}

// ===== fallback: round-6-proven generic kernel (swizzled img or gather) =====
__global__ __launch_bounds__(512) void gemm_kernel(
    const float* __restrict__ kv,
    const float* __restrict__ biasK, const float* __restrict__ biasV,
    const unsigned short* __restrict__ imgK, const unsigned short* __restrict__ imgV,
    const float* __restrict__ kw, const float* __restrict__ vw,
    float* __restrict__ out,
    int selbase, int vbase, int nc, int ltot, int nsteps,
    int tokmax, int seqb, int strideh, int KSd, int mtiles) {
  __shared__ __align__(16) unsigned short As[2][4096];
  __shared__ __align__(16) unsigned short Bsf[2][8192];
  int tid = threadIdx.x, bid = blockIdx.x;
  int per_sel = 8 * mtiles;
  int sel = selbase + (bid >= per_sel);
  int rem = (bid >= per_sel) ? bid - per_sel : bid;
  int h = rem / mtiles, mtile = rem - h * mtiles;
  int m0 = mtile * 64;
  const unsigned short* img = sel ? imgV : imgK;
  const float* bias = sel ? biasV : biasK;
  const float* wsel = sel ? vw : kw;
  int outbase = sel ? vbase : 0;
  int lane = tid & 63, wid = tid >> 6;
  int warpM = wid >> 2, warpN = wid & 3;

  int aj = tid & 7, r = tid >> 3;
  int l = m0 + r; if (l > ltot - 1) l = ltot - 1;
  int b = l / nc, c = l - b * nc;
  int btok = b * seqb + c * strideh;
  const float* abase = kv + sel * 1024 + h * 128 + aj * 4;
  int swr = (r & 7) << 3;
  int awb0 = r * 128 + 2 * ((aj * 4) ^ swr);
  int awb1 = r * 128 + 2 * ((aj * 4 + 32) ^ swr);

  int o_g = tid >> 3, cb_g = (tid & 7) << 3;
  int ib_g = cb_g ^ ((o_g & 7) << 3);
  const float* g0 = wsel + (size_t)o_g * (KSd << 7);
  const float* g1 = g0 + ((size_t)64 * (KSd << 7));

  int kb0 = (lane >> 4) * 16;
  int arb[2], asw[2], brb[2], bsw[2];
#pragma unroll
  for (int mi = 0; mi < 2; ++mi) {
    int rr = warpM * 32 + mi * 16 + (lane & 15);
    arb[mi] = rr * 128; asw[mi] = (rr & 7) << 4;
  }
#pragma unroll
  for (int ni = 0; ni < 2; ++ni) {
    int oo = warpN * 32 + ni * 16 + (lane & 15);
    brb[ni] = oo * 128; bsw[ni] = (oo & 7) << 4;
  }

  f32x4 acc[2][2];
  f32x4 zz = {0.f, 0.f, 0.f, 0.f};
#pragma unroll
  for (int a = 0; a < 2; ++a)
#pragma unroll
    for (int b2 = 0; b2 < 2; ++b2) acc[a][b2] = zz;

  float4 Af0, Af1;
  uint4 Brr[2];

#define LOAD_STEP(S) do {                                                        \
    int tok_ = btok + ((S) >> 1); if (tok_ > tokmax) tok_ = tokmax;              \
    const float* ap_ = abase + ((size_t)tok_ << 11) + (((S) & 1) << 6);          \
    Af0 = *(const float4*)ap_;                                                   \
    Af1 = *(const float4*)(ap_ + 32);                                            \
    if (img) {                                                                   \
      const uint4* bsrc_ = (const uint4*)(img + ((size_t)(S) << 13));            \
      Brr[0] = bsrc_[tid];                                                       \
      Brr[1] = bsrc_[512 + tid];                                                 \
    } else {                                                                     \
      int t_ = (S) >> 1, i0_ = (((S) & 1) << 6) + ib_g;                          \
      unsigned int p0_[4], p1_[4];                                               \
      _Pragma("unroll")                                                          \
      for (int m = 0; m < 4; ++m) {                                              \
        p0_[m] = (unsigned int)f2bf(g0[(i0_ + 2*m) * KSd + t_])                  \
               | ((unsigned int)f2bf(g0[(i0_ + 2*m + 1) * KSd + t_]) << 16);     \
        p1_[m] = (unsigned int)f2bf(g1[(i0_ + 2*m) * KSd + t_])                  \
               | ((unsigned int)f2bf(g1[(i0_ + 2*m + 1) * KSd + t_]) << 16);     \
      }                                                                          \
      Brr[0] = make_uint4(p0_[0], p0_[1], p0_[2], p0_[3]);                       \
      Brr[1] = make_uint4(p1_[0], p1_[1], p1_[2], p1_[3]);                       \
    }                                                                            \
  } while (0)

#define WRITE_STEP(DB) do {                                                      \
    *(uint2*)((char*)As[DB] + awb0) = make_uint2(PK(Af0.x, Af0.y), PK(Af0.z, Af0.w)); \
    *(uint2*)((char*)As[DB] + awb1) = make_uint2(PK(Af1.x, Af1.y), PK(Af1.z, Af1.w)); \
    uint4* bdst_ = (uint4*)Bsf[DB];                                              \
    bdst_[tid] = Brr[0];                                                         \
    bdst_[512 + tid] = Brr[1];                                                   \
  } while (0)

#define COMPUTE_STEP(CB) do {                                                    \
    _Pragma("unroll")                                                            \
    for (int kk = 0; kk < 2; ++kk) {                                             \
      bf16x8 af_[2], bg_[2];                                                     \
      int kc_ = kk * 64 + kb0;                                                   \
      _Pragma("unroll")                                                          \
      for (int mi = 0; mi < 2; ++mi)                                             \
        af_[mi] = *(const bf16x8*)((const char*)As[CB] + arb[mi] + (kc_ ^ asw[mi])); \
      _Pragma("unroll")                                                          \
      for (int ni = 0; ni < 2; ++ni)                                             \
        bg_[ni] = *(const bf16x8*)((const char*)Bsf[CB] + brb[ni] + (kc_ ^ bsw[ni])); \
      _Pragma("unroll")                                                          \
      for (int mi = 0; mi < 2; ++mi)                                             \
      _Pragma("unroll")                                                          \
        for (int ni = 0; ni < 2; ++ni)                                           \
          acc[mi][ni] = MFMA16(af_[mi], bg_[ni], acc[mi][ni]);                   \
    }                                                                            \
  } while (0)

  LOAD_STEP(0);
  WRITE_STEP(0);
  __syncthreads();
  int cur = 0;
  for (int s = 0; s < nsteps; ++s) {
    if (s + 1 < nsteps) LOAD_STEP(s + 1);
    COMPUTE_STEP(cur);
    if (s + 1 < nsteps) WRITE_STEP(cur ^ 1);
    __syncthreads();
    cur ^= 1;
  }

  int l15 = lane & 15, l4 = lane >> 4;
#pragma unroll
  for (int ni = 0; ni < 2; ++ni) {
    int o = warpN * 32 + ni * 16 + l15;
    float bv = bias[o];
#pragma unroll
    for (int mi = 0; mi < 2; ++mi) {
      int lb = m0 + warpM * 32 + mi * 16 + l4 * 4;
      f32x4 v = acc[mi][ni];
#pragma unroll
      for (int jj = 0; jj < 4; ++jj) {
        int ll = lb + jj;
        if (ll < ltot)
          out[(size_t)outbase + (size_t)ll * 1024 + h * 128 + o] = v[jj] + bv;
      }
    }
  }
}

extern "C" void kernel_launch(void* const* d_in, const int* in_sizes, int n_in,
                              void* d_out, int out_size, void* d_ws, size_t ws_size,
                              hipStream_t stream) {
  // ---- identify inputs by element count (robust to order) ----
  long kvN = 0; int kvi = 0;
  for (int i = 0; i < n_in; ++i)
    if ((long)in_sizes[i] > kvN) { kvN = in_sizes[i]; kvi = i; }
  const float* kv = (const float*)d_in[kvi];
  const float *w0 = nullptr, *w1 = nullptr, *b0 = nullptr, *b1 = nullptr;
  const int* cuin = nullptr;
  int KSd = 32, nb = 4;
  for (int i = 0; i < n_in; ++i) {
    if (i == kvi) continue;
    int sz = in_sizes[i];
    if (sz == 128) { if (!b0) b0 = (const float*)d_in[i]; else if (!b1) b1 = (const float*)d_in[i]; }
    else if (sz <= 32) { nb = sz - 1; cuin = (const int*)d_in[i]; }
    else if (sz >= 4096) {
      if (!w0) { w0 = (const float*)d_in[i]; KSd = sz / 16384; }
      else if (!w1) w1 = (const float*)d_in[i];
    }
  }
  if (!w0) w0 = (const float*)d_in[2];
  if (!b0) b0 = (const float*)d_in[3];
  if (!w1) w1 = (const float*)d_in[4];
  if (!b1) b1 = (const float*)d_in[5];
  if (!cuin) cuin = (const int*)d_in[1];
  if (nb < 1) nb = 4;

  float* out = (float*)d_out;

  // ---- geometry derived from reported sizes ----
  int cubase  = out_size - (nb + 1);
  int vbase   = cubase >> 1;
  int ltot    = cubase >> 11;
  int nc      = ltot / nb;
  int nsteps  = 2 * KSd;
  long tokens = kvN >> 11;
  int seqb    = (int)(tokens / nb);
  int strideh = (nc > 1) ? (seqb - KSd) / (nc - 1) : KSd;
  int tokmax  = (int)tokens - 1;
  int mtiles  = (ltot + 63) >> 6;      // 64-row tiles (fallback)
  int mt128   = (ltot + 127) >> 7;     // 128-row tiles (fast path)
  int per_sel = 8 * mtiles;

  size_t imgel = (size_t)nsteps * 8192;
  size_t imgbytes = imgel * 2;
  bool fast = (KSd == 32) && (strideh == 16) && (nc >= 128) &&
              (ws_size >= 2 * imgbytes);
  if (fast) {
    unsigned short* imgK = (unsigned short*)d_ws;
    unsigned short* imgV = imgK + imgel;
    prep_kernel<<<256, 256, 0, stream>>>(w0, w1, imgK, imgV, KSd,
                                         cuin, out, cubase, nb, strideh);
    gemm_big_kernel<<<2 * 8 * mt128, 512, 0, stream>>>(
        kv, b0, b1, imgK, imgV, out, vbase, nc, ltot, tokmax, seqb, mt128);
  } else if (ws_size >= 2 * imgbytes) {
    unsigned short* imgK = (unsigned short*)d_ws;
    unsigned short* imgV = imgK + imgel;
    prep_kernel<<<256, 256, 0, stream>>>(w0, w1, imgK, imgV, KSd,
                                         cuin, out, cubase, nb, strideh);
    gemm_kernel<<<2 * per_sel, 512, 0, stream>>>(kv, b0, b1, imgK, imgV, w0, w1, out,
        0, vbase, nc, ltot, nsteps, tokmax, seqb, strideh, KSd, mtiles);
  } else {
    prep_kernel<<<256, 256, 0, stream>>>(w0, w1, (unsigned short*)d_ws,
                                         (unsigned short*)d_ws, 0,
                                         cuin, out, cubase, nb, strideh);
    gemm_kernel<<<2 * per_sel, 512, 0, stream>>>(kv, b0, b1,
        (const unsigned short*)nullptr, (const unsigned short*)nullptr, w0, w1, out,
        0, vbase, nc, ltot, nsteps, tokmax, seqb, strideh, KSd, mtiles);
  }
}